// Round 2
// baseline (56.811 us; speedup 1.0000x reference)
//
#include <hip/hip_runtime.h>

// The entire 4-wire / 4-layer circuit reduces analytically to out = cos(x):
//  - RZ layers are diagonal unit-modulus phases -> do not change |amp|^2.
//  - The CNOT chain 0->1->2->3 is the GF(2) map M = I + S (S = bit shift);
//    M^4 = I on 4 bits, so the composed permutation over 4 layers is identity.
//  - probs == initial product-state probs; <Z_w> = cos^2(x_w/2)-sin^2(x_w/2)
//    = cos(x_w). Weights drop out entirely.
//
// 2 float4 per thread (two coalesced passes, loads issued back-to-back) to
// halve workgroup count and overlap the two VMEM loads.
__global__ __launch_bounds__(256) void QuantumKernel_65481071407639_kernel(
    const float4* __restrict__ x, float4* __restrict__ out, int n4) {
    int i = blockIdx.x * blockDim.x + threadIdx.x;
    int stride = gridDim.x * blockDim.x;
    int j = i + stride;
    float4 v0, v1;
    bool ok0 = (i < n4);
    bool ok1 = (j < n4);
    if (ok0) v0 = x[i];
    if (ok1) v1 = x[j];
    if (ok0) {
        float4 r;
        r.x = __cosf(v0.x); r.y = __cosf(v0.y);
        r.z = __cosf(v0.z); r.w = __cosf(v0.w);
        out[i] = r;
    }
    if (ok1) {
        float4 r;
        r.x = __cosf(v1.x); r.y = __cosf(v1.y);
        r.z = __cosf(v1.z); r.w = __cosf(v1.w);
        out[j] = r;
    }
}

extern "C" void kernel_launch(void* const* d_in, const int* in_sizes, int n_in,
                              void* d_out, int out_size, void* d_ws, size_t ws_size,
                              hipStream_t stream) {
    const float4* x = (const float4*)d_in[0];   // (262144, 4) fp32
    float4* out = (float4*)d_out;               // (262144, 4) fp32
    int n4 = out_size / 4;                      // 262144 float4 groups
    int block = 256;
    int per_block = block * 2;                  // 2 float4 per thread
    int grid = (n4 + per_block - 1) / per_block; // 512 blocks
    QuantumKernel_65481071407639_kernel<<<grid, block, 0, stream>>>(x, out, n4);
}